// Round 4
// baseline (202.413 us; speedup 1.0000x reference)
//
#include <hip/hip_runtime.h>

#define LSEQ 4096
#define EMB  1024
#define NH   16
#define HD   64

typedef __attribute__((ext_vector_type(8))) __bf16 bf16x8;
typedef __attribute__((ext_vector_type(4))) float f32x4;
typedef __attribute__((ext_vector_type(8))) unsigned short u16x8;
typedef __attribute__((ext_vector_type(4))) unsigned short u16x4;

// byte offset of 16B chunk `c` in row `r` of a [*][64]-short tile, XOR-swizzled
#define SWZ(r, c) (((r) * 128) + ((((c) ^ ((r) & 7))) << 4))

__device__ __forceinline__ unsigned short f2bf(float f) {
    union { float f; unsigned u; } v; v.f = f;
    unsigned r = v.u + 0x7fffu + ((v.u >> 16) & 1u);
    return (unsigned short)(r >> 16);
}

__device__ __forceinline__ unsigned cvt_pk_bf16(float a, float b) {
    unsigned r;
    asm("v_cvt_pk_bf16_f32 %0, %1, %2" : "=v"(r) : "v"(a), "v"(b));
    return r;
}

__device__ __forceinline__ f32x4 mfma16(u16x8 a, u16x8 b, f32x4 c) {
    return __builtin_amdgcn_mfma_f32_16x16x32_bf16(
        __builtin_bit_cast(bf16x8, a), __builtin_bit_cast(bf16x8, b), c, 0, 0, 0);
}

__device__ __forceinline__ void gload16(const void* g, void* l) {
    __builtin_amdgcn_global_load_lds((const __attribute__((address_space(1))) unsigned int*)g,
                                     (__attribute__((address_space(3))) unsigned int*)l,
                                     16, 0, 0);
}

// ---------------- fused fp32 -> bf16 convert (single launch, contiguous dest) ----------------
#define NX (LSEQ * EMB / 4)
#define NA (3 * EMB * EMB / 4)
#define NP (EMB * EMB / 4)
__global__ __launch_bounds__(256) void cvt_all(const float* __restrict__ x,
                                               const float* __restrict__ wa,
                                               const float* __restrict__ wp,
                                               unsigned short* __restrict__ out) {
    int i = blockIdx.x * 256 + threadIdx.x;
    if (i >= NX + NA + NP) return;
    const float* src;
    if (i < NX)            src = x + (size_t)i * 4;
    else if (i < NX + NA)  src = wa + (size_t)(i - NX) * 4;
    else                   src = wp + (size_t)(i - NX - NA) * 4;
    f32x4 v = *(const f32x4*)src;
    u16x4 o;
    o[0] = f2bf(v[0]); o[1] = f2bf(v[1]); o[2] = f2bf(v[2]); o[3] = f2bf(v[3]);
    *(u16x4*)(out + (size_t)i * 4) = o;
}

// ---------------- QKV GEMM: C[M=L,N=3E] = X[L,E] * Wattn^T, scatter epilogue ----------------
// Q pre-scaled by 0.125*log2(e) so attention softmax can use exp2 directly.
__global__ __launch_bounds__(256, 2) void gemm_qkv(const unsigned short* __restrict__ A,
                                                   const unsigned short* __restrict__ B,
                                                   unsigned short* __restrict__ Qo,
                                                   unsigned short* __restrict__ Ko,
                                                   unsigned short* __restrict__ Vto) {
    __shared__ unsigned short As[128 * 32];
    __shared__ unsigned short Bs[128 * 32];
    const int tid = threadIdx.x;
    const int lane = tid & 63;
    const int wv = tid >> 6;
    const int wm = wv >> 1, wn = wv & 1;
    const int li = lane & 15, g = lane >> 4;
    const int m0 = blockIdx.y * 128, n0 = blockIdx.x * 128;
    f32x4 acc[4][4] = {};
    for (int k0 = 0; k0 < EMB; k0 += 32) {
        #pragma unroll
        for (int c = 0; c < 2; ++c) {
            const int o = c * 4096 + tid * 16;
            const int r = o >> 6, cb = o & 63;
            gload16((const char*)A + ((size_t)(m0 + r) * EMB + k0) * 2 + cb, (char*)As + o);
            gload16((const char*)B + ((size_t)(n0 + r) * EMB + k0) * 2 + cb, (char*)Bs + o);
        }
        __syncthreads();
        u16x8 af[4], bfr[4];
        #pragma unroll
        for (int mb = 0; mb < 4; ++mb)
            af[mb] = *(const u16x8*)(As + (wm * 64 + mb * 16 + li) * 32 + g * 8);
        #pragma unroll
        for (int nb = 0; nb < 4; ++nb)
            bfr[nb] = *(const u16x8*)(Bs + (wn * 64 + nb * 16 + li) * 32 + g * 8);
        #pragma unroll
        for (int mb = 0; mb < 4; ++mb)
            #pragma unroll
            for (int nb = 0; nb < 4; ++nb)
                acc[mb][nb] = mfma16(af[mb], bfr[nb], acc[mb][nb]);
        __syncthreads();
    }
    for (int mb = 0; mb < 4; ++mb) {
        for (int nb = 0; nb < 4; ++nb) {
            for (int r = 0; r < 4; ++r) {
                const int m = m0 + wm * 64 + mb * 16 + g * 4 + r;
                const int n = n0 + wn * 64 + nb * 16 + li;
                const float v = acc[mb][nb][r];
                if (n < EMB) {
                    // 0.125 * log2(e): softmax runs in exp2 domain
                    Qo[((size_t)(n >> 6) * LSEQ + m) * HD + (n & 63)] = f2bf(v * 0.1803368801111244f);
                } else if (n < 2 * EMB) {
                    const int c = n - EMB;
                    Ko[((size_t)(c >> 6) * LSEQ + m) * HD + (c & 63)] = f2bf(v);
                } else {
                    const int c = n - 2 * EMB;
                    Vto[((size_t)(c >> 6) * HD + (c & 63)) * LSEQ + m] = f2bf(v);
                }
            }
        }
    }
}

// ---------------- flash attention (causal), swapped QK^T, one q-tile per block ----------------
// grid (64, 16), qt = 63 - blockIdx.x (heaviest blocks dispatch first).
// 4 blocks/CU (LDS 40960 x 4 = 160KB exactly), 16 waves/CU.
__global__ __launch_bounds__(256, 4) void attn_fwd(const unsigned short* __restrict__ Q,
                                                   const unsigned short* __restrict__ K,
                                                   const unsigned short* __restrict__ Vt,
                                                   unsigned short* __restrict__ Y) {
    __shared__ unsigned short Ks[2][64][64];
    __shared__ unsigned short Vs[2][64][64];   // V^T tile: [hd][kv]
    __shared__ unsigned short Ps[4][16][64];   // per-wave P[q_local][k]
    const int h = blockIdx.y;
    const int tid = threadIdx.x, lane = tid & 63, w = tid >> 6;
    const int g = lane >> 4, li = lane & 15;
    const int srow = tid >> 2, scb = (tid & 3) * 2;
    char* KsB = (char*)Ks;
    char* VsB = (char*)Vs;
    char* PsB = (char*)Ps + w * 2048;
    const unsigned short* Kh = K + (size_t)h * LSEQ * HD;
    const unsigned short* Vh = Vt + (size_t)h * HD * LSEQ;

    const int qt = 63 - (int)blockIdx.x;
    const int q0 = qt * 64;
    const int jmax = qt;
    const int qlane = q0 + w * 16 + li;
    const unsigned short* qrow = Q + ((size_t)h * LSEQ + qlane) * HD;
    const u16x8 bq0 = *(const u16x8*)(qrow + g * 8);
    const u16x8 bq1 = *(const u16x8*)(qrow + 32 + g * 8);
    float m_i = -1e30f, l_i = 0.f;
    f32x4 accO[4] = {};
    {   // prologue: stage tile 0 -> buf 0
        const unsigned short* kp = Kh + (size_t)srow * HD + (tid & 3) * 16;
        const unsigned short* vp = Vh + (size_t)srow * LSEQ + (tid & 3) * 16;
        u16x8 a0 = *(const u16x8*)kp, a1 = *(const u16x8*)(kp + 8);
        u16x8 b0 = *(const u16x8*)vp, b1 = *(const u16x8*)(vp + 8);
        *(u16x8*)(KsB + SWZ(srow, scb))     = a0;
        *(u16x8*)(KsB + SWZ(srow, scb + 1)) = a1;
        *(u16x8*)(VsB + SWZ(srow, scb))     = b0;
        *(u16x8*)(VsB + SWZ(srow, scb + 1)) = b1;
    }
    __syncthreads();
    for (int j = 0; j <= jmax; ++j) {
        const int cur = j & 1;
        const int cbuf = cur * 8192;
        const bool pf = (j < jmax);
        u16x8 kn0, kn1, vn0, vn1;
        if (pf) {   // T14: issue next-tile global loads early
            const unsigned short* kp = Kh + (size_t)(j + 1) * 64 * HD + (size_t)srow * HD + (tid & 3) * 16;
            const unsigned short* vp = Vh + (size_t)srow * LSEQ + (j + 1) * 64 + (tid & 3) * 16;
            kn0 = *(const u16x8*)kp; kn1 = *(const u16x8*)(kp + 8);
            vn0 = *(const u16x8*)vp; vn1 = *(const u16x8*)(vp + 8);
        }
        const int kbase = j * 64;
        {
            u16x8 bv0[4], bv1[4];
            #pragma unroll
            for (int o = 0; o < 4; ++o) {
                bv0[o] = *(const u16x8*)(VsB + cbuf + SWZ(o * 16 + li, g));
                bv1[o] = *(const u16x8*)(VsB + cbuf + SWZ(o * 16 + li, 4 + g));
            }
            f32x4 s[4];
            __builtin_amdgcn_s_setprio(1);
            #pragma unroll
            for (int jb = 0; jb < 4; ++jb) {
                const u16x8 ka0 = *(const u16x8*)(KsB + cbuf + SWZ(jb * 16 + li, g));
                const u16x8 ka1 = *(const u16x8*)(KsB + cbuf + SWZ(jb * 16 + li, 4 + g));
                f32x4 a = {};
                a = mfma16(ka0, bq0, a);
                a = mfma16(ka1, bq1, a);
                s[jb] = a;
            }
            __builtin_amdgcn_s_setprio(0);
            if (kbase + 63 > q0 + w * 16) {
                #pragma unroll
                for (int jb = 0; jb < 4; ++jb)
                    #pragma unroll
                    for (int r = 0; r < 4; ++r)
                        if (kbase + jb * 16 + g * 4 + r > qlane) s[jb][r] = -1e30f;
            }
            float mt = s[0][0];
            #pragma unroll
            for (int jb = 0; jb < 4; ++jb)
                #pragma unroll
                for (int r = 0; r < 4; ++r) mt = fmaxf(mt, s[jb][r]);
            mt = fmaxf(mt, __shfl_xor(mt, 16));
            mt = fmaxf(mt, __shfl_xor(mt, 32));
            // T13 defer-max (log2 domain: max P = 2^8 = 256)
            const bool need = !__all(mt - m_i <= 8.0f);
            float al = 1.0f;
            if (need) {
                const float mn = fmaxf(m_i, mt);
                al = exp2f(m_i - mn);
                m_i = mn;
            }
            float p[4][4], sum = 0.f;
            #pragma unroll
            for (int jb = 0; jb < 4; ++jb)
                #pragma unroll
                for (int r = 0; r < 4; ++r) {
                    p[jb][r] = exp2f(s[jb][r] - m_i);
                    sum += p[jb][r];
                }
            sum += __shfl_xor(sum, 16);
            sum += __shfl_xor(sum, 32);
            #pragma unroll
            for (int jb = 0; jb < 4; ++jb) {
                uint2 pv;
                pv.x = cvt_pk_bf16(p[jb][0], p[jb][1]);
                pv.y = cvt_pk_bf16(p[jb][2], p[jb][3]);
                *(uint2*)(PsB + SWZ(li, jb * 2 + (g >> 1)) + (g & 1) * 8) = pv;
            }
            l_i = l_i * al + sum;
            if (need) {
                float alq[4];
                #pragma unroll
                for (int r = 0; r < 4; ++r) alq[r] = __shfl(al, g * 4 + r);
                #pragma unroll
                for (int o = 0; o < 4; ++o)
                    #pragma unroll
                    for (int r = 0; r < 4; ++r) accO[o][r] *= alq[r];
            }
            asm volatile("s_waitcnt lgkmcnt(0)" ::: "memory");
            __builtin_amdgcn_sched_barrier(0);
            const u16x8 ap0 = *(const u16x8*)(PsB + SWZ(li, g));
            const u16x8 ap1 = *(const u16x8*)(PsB + SWZ(li, 4 + g));
            __builtin_amdgcn_s_setprio(1);
            #pragma unroll
            for (int o = 0; o < 4; ++o) {
                accO[o] = mfma16(ap0, bv0[o], accO[o]);
                accO[o] = mfma16(ap1, bv1[o], accO[o]);
            }
            __builtin_amdgcn_s_setprio(0);
        }
        if (pf) {
            const int nb = (cur ^ 1) * 8192;
            *(u16x8*)(KsB + nb + SWZ(srow, scb))     = kn0;
            *(u16x8*)(KsB + nb + SWZ(srow, scb + 1)) = kn1;
            *(u16x8*)(VsB + nb + SWZ(srow, scb))     = vn0;
            *(u16x8*)(VsB + nb + SWZ(srow, scb + 1)) = vn1;
        }
        __syncthreads();
    }
    float lq[4];
    #pragma unroll
    for (int r = 0; r < 4; ++r) lq[r] = __shfl(l_i, g * 4 + r);
    #pragma unroll
    for (int o = 0; o < 4; ++o)
        #pragma unroll
        for (int r = 0; r < 4; ++r) {
            const int row = q0 + w * 16 + g * 4 + r;
            Y[(size_t)row * EMB + h * HD + o * 16 + li] = f2bf(accO[o][r] / lq[r]);
        }
}

// ---------------- proj GEMM: out[L,E] fp32 = Y[L,E] * Wproj^T ----------------
__global__ __launch_bounds__(256, 2) void gemm_proj(const unsigned short* __restrict__ A,
                                                    const unsigned short* __restrict__ B,
                                                    float* __restrict__ C) {
    __shared__ unsigned short As[128 * 32];
    __shared__ unsigned short Bs[128 * 32];
    const int tid = threadIdx.x;
    const int lane = tid & 63;
    const int wv = tid >> 6;
    const int wm = wv >> 1, wn = wv & 1;
    const int li = lane & 15, g = lane >> 4;
    const int m0 = blockIdx.y * 128, n0 = blockIdx.x * 128;
    f32x4 acc[4][4] = {};
    for (int k0 = 0; k0 < EMB; k0 += 32) {
        #pragma unroll
        for (int c = 0; c < 2; ++c) {
            const int o = c * 4096 + tid * 16;
            const int r = o >> 6, cb = o & 63;
            gload16((const char*)A + ((size_t)(m0 + r) * EMB + k0) * 2 + cb, (char*)As + o);
            gload16((const char*)B + ((size_t)(n0 + r) * EMB + k0) * 2 + cb, (char*)Bs + o);
        }
        __syncthreads();
        u16x8 af[4], bfr[4];
        #pragma unroll
        for (int mb = 0; mb < 4; ++mb)
            af[mb] = *(const u16x8*)(As + (wm * 64 + mb * 16 + li) * 32 + g * 8);
        #pragma unroll
        for (int nb = 0; nb < 4; ++nb)
            bfr[nb] = *(const u16x8*)(Bs + (wn * 64 + nb * 16 + li) * 32 + g * 8);
        #pragma unroll
        for (int mb = 0; mb < 4; ++mb)
            #pragma unroll
            for (int nb = 0; nb < 4; ++nb)
                acc[mb][nb] = mfma16(af[mb], bfr[nb], acc[mb][nb]);
        __syncthreads();
    }
    for (int mb = 0; mb < 4; ++mb)
        for (int nb = 0; nb < 4; ++nb)
            for (int r = 0; r < 4; ++r) {
                const int m = m0 + wm * 64 + mb * 16 + g * 4 + r;
                const int n = n0 + wn * 64 + nb * 16 + li;
                C[(size_t)m * EMB + n] = acc[mb][nb][r];
            }
}

extern "C" void kernel_launch(void* const* d_in, const int* in_sizes, int n_in,
                              void* d_out, int out_size, void* d_ws, size_t ws_size,
                              hipStream_t stream) {
    const float* x      = (const float*)d_in[0];
    const float* w_attn = (const float*)d_in[1];
    const float* w_proj = (const float*)d_in[2];
    float* out = (float*)d_out;

    unsigned short* ws  = (unsigned short*)d_ws;
    unsigned short* xb  = ws;
    unsigned short* wab = xb + (size_t)LSEQ * EMB;
    unsigned short* wpb = wab + (size_t)3 * EMB * EMB;
    unsigned short* Qb  = wpb + (size_t)EMB * EMB;
    unsigned short* Kb  = Qb + (size_t)LSEQ * EMB;
    unsigned short* Vtb = Kb + (size_t)LSEQ * EMB;
    unsigned short* Yb  = Vtb + (size_t)LSEQ * EMB;

    const int ntot = NX + NA + NP;
    cvt_all<<<(ntot + 255) / 256, 256, 0, stream>>>(x, w_attn, w_proj, xb);
    gemm_qkv<<<dim3(3 * EMB / 128, LSEQ / 128), 256, 0, stream>>>(xb, wab, Qb, Kb, Vtb);
    attn_fwd<<<dim3(64, NH), 256, 0, stream>>>(Qb, Kb, Vtb, Yb);
    gemm_proj<<<dim3(EMB / 128, LSEQ / 128), 256, 0, stream>>>(Yb, wpb, out);
}

// Round 5
// 166.132 us; speedup vs baseline: 1.2184x; 1.2184x over previous
//
#include <hip/hip_runtime.h>

#define LSEQ 4096
#define EMB  1024
#define NH   16
#define HD   64

typedef __attribute__((ext_vector_type(8))) __bf16 bf16x8;
typedef __attribute__((ext_vector_type(4))) float f32x4;
typedef __attribute__((ext_vector_type(8))) unsigned short u16x8;
typedef __attribute__((ext_vector_type(4))) unsigned short u16x4;

// byte offset of 16B chunk `c` (0..7) in row `r` of a [*][64]-short tile, XOR-swizzled
#define SWZ(r, c) (((r) * 128) + ((((c) ^ ((r) & 7))) << 4))

__device__ __forceinline__ unsigned short f2bf(float f) {
    union { float f; unsigned u; } v; v.f = f;
    unsigned r = v.u + 0x7fffu + ((v.u >> 16) & 1u);
    return (unsigned short)(r >> 16);
}

__device__ __forceinline__ unsigned cvt_pk_bf16(float a, float b) {
    unsigned r;
    asm("v_cvt_pk_bf16_f32 %0, %1, %2" : "=v"(r) : "v"(a), "v"(b));
    return r;
}

__device__ __forceinline__ f32x4 mfma16(u16x8 a, u16x8 b, f32x4 c) {
    return __builtin_amdgcn_mfma_f32_16x16x32_bf16(
        __builtin_bit_cast(bf16x8, a), __builtin_bit_cast(bf16x8, b), c, 0, 0, 0);
}

__device__ __forceinline__ void gload16(const void* g, void* l) {
    __builtin_amdgcn_global_load_lds((const __attribute__((address_space(1))) unsigned int*)g,
                                     (__attribute__((address_space(3))) unsigned int*)l,
                                     16, 0, 0);
}

// ---------------- fused fp32 -> bf16 convert ----------------
#define NXC (LSEQ * EMB / 4)
#define NAC (3 * EMB * EMB / 4)
#define NPC (EMB * EMB / 4)
__global__ __launch_bounds__(256) void cvt_all(const float* __restrict__ x,
                                               const float* __restrict__ wa,
                                               const float* __restrict__ wp,
                                               unsigned short* __restrict__ out) {
    int i = blockIdx.x * 256 + threadIdx.x;
    if (i >= NXC + NAC + NPC) return;
    const float* src;
    if (i < NXC)             src = x + (size_t)i * 4;
    else if (i < NXC + NAC)  src = wa + (size_t)(i - NXC) * 4;
    else                     src = wp + (size_t)(i - NXC - NAC) * 4;
    f32x4 v = *(const f32x4*)src;
    u16x4 o;
    o[0] = f2bf(v[0]); o[1] = f2bf(v[1]); o[2] = f2bf(v[2]); o[3] = f2bf(v[3]);
    *(u16x4*)(out + (size_t)i * 4) = o;
}

// ---------------- QKV GEMM: C[M=L,N=3E] = X[L,E] * Wattn^T, scatter epilogue ----------------
// Q pre-scaled by 0.125*log2(e): attention softmax runs in exp2 domain.
__global__ __launch_bounds__(256, 2) void gemm_qkv(const unsigned short* __restrict__ A,
                                                   const unsigned short* __restrict__ B,
                                                   unsigned short* __restrict__ Qo,
                                                   unsigned short* __restrict__ Ko,
                                                   unsigned short* __restrict__ Vto) {
    __shared__ unsigned short As[128 * 32];
    __shared__ unsigned short Bs[128 * 32];
    const int tid = threadIdx.x;
    const int lane = tid & 63;
    const int wv = tid >> 6;
    const int wm = wv >> 1, wn = wv & 1;
    const int li = lane & 15, g = lane >> 4;
    const int m0 = blockIdx.y * 128, n0 = blockIdx.x * 128;
    f32x4 acc[4][4] = {};
    for (int k0 = 0; k0 < EMB; k0 += 32) {
        #pragma unroll
        for (int c = 0; c < 2; ++c) {
            const int o = c * 4096 + tid * 16;
            const int r = o >> 6, cb = o & 63;
            gload16((const char*)A + ((size_t)(m0 + r) * EMB + k0) * 2 + cb, (char*)As + o);
            gload16((const char*)B + ((size_t)(n0 + r) * EMB + k0) * 2 + cb, (char*)Bs + o);
        }
        __syncthreads();
        u16x8 af[4], bfr[4];
        #pragma unroll
        for (int mb = 0; mb < 4; ++mb)
            af[mb] = *(const u16x8*)(As + (wm * 64 + mb * 16 + li) * 32 + g * 8);
        #pragma unroll
        for (int nb = 0; nb < 4; ++nb)
            bfr[nb] = *(const u16x8*)(Bs + (wn * 64 + nb * 16 + li) * 32 + g * 8);
        #pragma unroll
        for (int mb = 0; mb < 4; ++mb)
            #pragma unroll
            for (int nb = 0; nb < 4; ++nb)
                acc[mb][nb] = mfma16(af[mb], bfr[nb], acc[mb][nb]);
        __syncthreads();
    }
    for (int mb = 0; mb < 4; ++mb) {
        for (int nb = 0; nb < 4; ++nb) {
            for (int r = 0; r < 4; ++r) {
                const int m = m0 + wm * 64 + mb * 16 + g * 4 + r;
                const int n = n0 + wn * 64 + nb * 16 + li;
                const float v = acc[mb][nb][r];
                if (n < EMB) {
                    Qo[((size_t)(n >> 6) * LSEQ + m) * HD + (n & 63)] = f2bf(v * 0.1803368801111244f);
                } else if (n < 2 * EMB) {
                    const int c = n - EMB;
                    Ko[((size_t)(c >> 6) * LSEQ + m) * HD + (c & 63)] = f2bf(v);
                } else {
                    const int c = n - 2 * EMB;
                    Vto[((size_t)(c >> 6) * HD + (c & 63)) * LSEQ + m] = f2bf(v);
                }
            }
        }
    }
}

// ---------------- flash attention (causal), swapped QK^T ----------------
// grid (32,16), 512 threads = 8 waves: wave = (qsub = w&3, kv-parity = w>>2).
// Block does paired q-tiles (bx, 63-bx) sequentially => 65 tiles/block, perfectly balanced.
// Parity streams keep private (m,l,accO), merged per segment via LDS.
// LDS 48KB -> 2 blocks/CU = 16 waves/CU.
__global__ __launch_bounds__(512, 4) void attn_fwd(const unsigned short* __restrict__ Q,
                                                   const unsigned short* __restrict__ K,
                                                   const unsigned short* __restrict__ Vt,
                                                   unsigned short* __restrict__ Y) {
    __shared__ unsigned short Ks[2][64][64];   // [parity][kv_row][d]      16KB
    __shared__ unsigned short Vs[2][64][64];   // [parity][d][kv] (V^T)    16KB
    __shared__ unsigned short Ps[8][16][64];   // per-wave P[q_local][kv]  16KB
    float* mergeO  = (float*)Ks;               // overlay: par1 accO (4w*64l*16f = 16KB)
    float* mergeML = (float*)Vs;               // overlay: par1 m,l

    const int h = blockIdx.y;
    const int tid = threadIdx.x, lane = tid & 63, w = tid >> 6;
    const int qs = w & 3;       // q sub-tile (16 rows)
    const int par = w >> 2;     // kv parity stream
    const int g = lane >> 4, li = lane & 15;
    const int srow = tid >> 3, sc = tid & 7;   // staging: 64 rows x 8 chunks of 16B
    char* KsB = (char*)Ks;
    char* VsB = (char*)Vs;
    char* PsB = (char*)Ps + w * 2048;
    const unsigned short* Kh = K + (size_t)h * LSEQ * HD;
    const unsigned short* Vh = Vt + (size_t)h * HD * LSEQ;

    #pragma unroll 1
    for (int seg = 0; seg < 2; ++seg) {
        const int qt = seg ? (63 - (int)blockIdx.x) : (int)blockIdx.x;
        const int q0 = qt * 64;
        const int jmax = qt;
        const int npairs = (jmax + 2) >> 1;
        const int qlane = q0 + qs * 16 + li;
        const unsigned short* qrow = Q + ((size_t)h * LSEQ + qlane) * HD;
        const u16x8 bq0 = *(const u16x8*)(qrow + g * 8);
        const u16x8 bq1 = *(const u16x8*)(qrow + 32 + g * 8);
        float m_i = -1e30f, l_i = 0.f;
        f32x4 accO[4] = {};
        {   // prologue: stage pair 0 (tiles 0, min(1,jmax))
            const int j1 = (jmax >= 1) ? 1 : 0;
            u16x8 k0 = *(const u16x8*)(Kh + (size_t)srow * HD + sc * 8);
            u16x8 k1 = *(const u16x8*)(Kh + (size_t)(j1 * 64 + srow) * HD + sc * 8);
            u16x8 v0 = *(const u16x8*)(Vh + (size_t)srow * LSEQ + sc * 8);
            u16x8 v1 = *(const u16x8*)(Vh + (size_t)srow * LSEQ + j1 * 64 + sc * 8);
            *(u16x8*)(KsB + SWZ(srow, sc))        = k0;
            *(u16x8*)(KsB + 8192 + SWZ(srow, sc)) = k1;
            *(u16x8*)(VsB + SWZ(srow, sc))        = v0;
            *(u16x8*)(VsB + 8192 + SWZ(srow, sc)) = v1;
        }
        __syncthreads();
        for (int t = 0; t < npairs; ++t) {
            const bool pf = (t + 1 < npairs);
            u16x8 kn0, kn1, vn0, vn1;
            if (pf) {   // T14: issue next pair's global loads before compute
                const int ja = 2 * t + 2;
                const int jb2 = (2 * t + 3 <= jmax) ? (2 * t + 3) : ja;
                kn0 = *(const u16x8*)(Kh + (size_t)(ja * 64 + srow) * HD + sc * 8);
                kn1 = *(const u16x8*)(Kh + (size_t)(jb2 * 64 + srow) * HD + sc * 8);
                vn0 = *(const u16x8*)(Vh + (size_t)srow * LSEQ + ja * 64 + sc * 8);
                vn1 = *(const u16x8*)(Vh + (size_t)srow * LSEQ + jb2 * 64 + sc * 8);
            }
            const int j = 2 * t + par;
            const int kbase = j * 64;
            if (j <= jmax && kbase <= q0 + qs * 16 + 15) {   // wave-uniform
                const int cbuf = par * 8192;
                u16x8 bv0[4], bv1[4];
                #pragma unroll
                for (int o = 0; o < 4; ++o) {
                    bv0[o] = *(const u16x8*)(VsB + cbuf + SWZ(o * 16 + li, g));
                    bv1[o] = *(const u16x8*)(VsB + cbuf + SWZ(o * 16 + li, 4 + g));
                }
                f32x4 s[4];
                __builtin_amdgcn_s_setprio(1);
                #pragma unroll
                for (int jb = 0; jb < 4; ++jb) {
                    const u16x8 ka0 = *(const u16x8*)(KsB + cbuf + SWZ(jb * 16 + li, g));
                    const u16x8 ka1 = *(const u16x8*)(KsB + cbuf + SWZ(jb * 16 + li, 4 + g));
                    f32x4 a = {};
                    a = mfma16(ka0, bq0, a);
                    a = mfma16(ka1, bq1, a);
                    s[jb] = a;
                }
                __builtin_amdgcn_s_setprio(0);
                if (kbase + 63 > q0 + qs * 16) {
                    #pragma unroll
                    for (int jb = 0; jb < 4; ++jb)
                        #pragma unroll
                        for (int r = 0; r < 4; ++r)
                            if (kbase + jb * 16 + g * 4 + r > qlane) s[jb][r] = -1e30f;
                }
                float mt = s[0][0];
                #pragma unroll
                for (int jb = 0; jb < 4; ++jb)
                    #pragma unroll
                    for (int r = 0; r < 4; ++r) mt = fmaxf(mt, s[jb][r]);
                mt = fmaxf(mt, __shfl_xor(mt, 16));
                mt = fmaxf(mt, __shfl_xor(mt, 32));
                const bool need = !__all(mt - m_i <= 8.0f);   // T13, exp2 domain (P<=256)
                float al = 1.0f;
                if (need) {
                    const float mn = fmaxf(m_i, mt);
                    al = exp2f(m_i - mn);
                    m_i = mn;
                }
                float p[4][4], sum = 0.f;
                #pragma unroll
                for (int jb = 0; jb < 4; ++jb)
                    #pragma unroll
                    for (int r = 0; r < 4; ++r) {
                        p[jb][r] = exp2f(s[jb][r] - m_i);
                        sum += p[jb][r];
                    }
                sum += __shfl_xor(sum, 16);
                sum += __shfl_xor(sum, 32);
                #pragma unroll
                for (int jb = 0; jb < 4; ++jb) {
                    uint2 pv;
                    pv.x = cvt_pk_bf16(p[jb][0], p[jb][1]);
                    pv.y = cvt_pk_bf16(p[jb][2], p[jb][3]);
                    *(uint2*)(PsB + SWZ(li, jb * 2 + (g >> 1)) + (g & 1) * 8) = pv;
                }
                l_i = l_i * al + sum;
                if (need) {
                    float alq[4];
                    #pragma unroll
                    for (int r = 0; r < 4; ++r) alq[r] = __shfl(al, g * 4 + r);
                    #pragma unroll
                    for (int o = 0; o < 4; ++o)
                        #pragma unroll
                        for (int r = 0; r < 4; ++r) accO[o][r] *= alq[r];
                }
                asm volatile("s_waitcnt lgkmcnt(0)" ::: "memory");
                __builtin_amdgcn_sched_barrier(0);
                const u16x8 ap0 = *(const u16x8*)(PsB + SWZ(li, g));
                const u16x8 ap1 = *(const u16x8*)(PsB + SWZ(li, 4 + g));
                __builtin_amdgcn_s_setprio(1);
                #pragma unroll
                for (int o = 0; o < 4; ++o) {
                    accO[o] = mfma16(ap0, bv0[o], accO[o]);
                    accO[o] = mfma16(ap1, bv1[o], accO[o]);
                }
                __builtin_amdgcn_s_setprio(0);
            }
            __syncthreads();               // compute done; slots reusable
            if (pf) {
                *(u16x8*)(KsB + SWZ(srow, sc))        = kn0;
                *(u16x8*)(KsB + 8192 + SWZ(srow, sc)) = kn1;
                *(u16x8*)(VsB + SWZ(srow, sc))        = vn0;
                *(u16x8*)(VsB + 8192 + SWZ(srow, sc)) = vn1;
                __syncthreads();           // staged, ready (uniform: pf is block-uniform)
            }
        }
        // ---- merge parity streams (par1 -> scratch, par0 merges & writes) ----
        if (par == 1) {
            float* po = mergeO + ((size_t)(w - 4) * 64 + lane) * 16;
            #pragma unroll
            for (int o = 0; o < 4; ++o) *(f32x4*)(po + o * 4) = accO[o];
            float* pml = mergeML + ((w - 4) * 64 + lane) * 2;
            pml[0] = m_i; pml[1] = l_i;
        }
        __syncthreads();
        if (par == 0) {
            const float* po  = mergeO + ((size_t)w * 64 + lane) * 16;
            const float* pml = mergeML + (w * 64 + lane) * 2;
            const float m1 = pml[0], l1 = pml[1];
            const float mS = fmaxf(m_i, m1);
            const float f0 = exp2f(m_i - mS);
            const float f1 = exp2f(m1 - mS);
            const float lm = l_i * f0 + l1 * f1;
            float f0r[4], f1r[4], lr[4];
            #pragma unroll
            for (int r = 0; r < 4; ++r) {
                f0r[r] = __shfl(f0, g * 4 + r);
                f1r[r] = __shfl(f1, g * 4 + r);
                lr[r]  = __shfl(lm, g * 4 + r);
            }
            #pragma unroll
            for (int o = 0; o < 4; ++o)
                #pragma unroll
                for (int r = 0; r < 4; ++r) {
                    const int row = q0 + qs * 16 + g * 4 + r;
                    const float v = (accO[o][r] * f0r[r] + po[o * 4 + r] * f1r[r]) / lr[r];
                    Y[(size_t)row * EMB + h * HD + o * 16 + li] = f2bf(v);
                }
        }
        __syncthreads();   // scratch (Ks/Vs) free before next seg's prologue
    }
}

// ---------------- proj GEMM: out[L,E] fp32 = Y[L,E] * Wproj^T ----------------
__global__ __launch_bounds__(256, 2) void gemm_proj(const unsigned short* __restrict__ A,
                                                    const unsigned short* __restrict__ B,
                                                    float* __restrict__ C) {
    __shared__ unsigned short As[128 * 32];
    __shared__ unsigned short Bs[128 * 32];
    const int tid = threadIdx.x;
    const int lane = tid & 63;
    const int wv = tid >> 6;
    const int wm = wv >> 1, wn = wv & 1;
    const int li = lane & 15, g = lane >> 4;
    const int m0 = blockIdx.y * 128, n0 = blockIdx.x * 128;
    f32x4 acc[4][4] = {};
    for (int k0 = 0; k0 < EMB; k0 += 32) {
        #pragma unroll
        for (int c = 0; c < 2; ++c) {
            const int o = c * 4096 + tid * 16;
            const int r = o >> 6, cb = o & 63;
            gload16((const char*)A + ((size_t)(m0 + r) * EMB + k0) * 2 + cb, (char*)As + o);
            gload16((const char*)B + ((size_t)(n0 + r) * EMB + k0) * 2 + cb, (char*)Bs + o);
        }
        __syncthreads();
        u16x8 af[4], bfr[4];
        #pragma unroll
        for (int mb = 0; mb < 4; ++mb)
            af[mb] = *(const u16x8*)(As + (wm * 64 + mb * 16 + li) * 32 + g * 8);
        #pragma unroll
        for (int nb = 0; nb < 4; ++nb)
            bfr[nb] = *(const u16x8*)(Bs + (wn * 64 + nb * 16 + li) * 32 + g * 8);
        #pragma unroll
        for (int mb = 0; mb < 4; ++mb)
            #pragma unroll
            for (int nb = 0; nb < 4; ++nb)
                acc[mb][nb] = mfma16(af[mb], bfr[nb], acc[mb][nb]);
        __syncthreads();
    }
    for (int mb = 0; mb < 4; ++mb)
        for (int nb = 0; nb < 4; ++nb)
            for (int r = 0; r < 4; ++r) {
                const int m = m0 + wm * 64 + mb * 16 + g * 4 + r;
                const int n = n0 + wn * 64 + nb * 16 + li;
                C[(size_t)m * EMB + n] = acc[mb][nb][r];
            }
}

extern "C" void kernel_launch(void* const* d_in, const int* in_sizes, int n_in,
                              void* d_out, int out_size, void* d_ws, size_t ws_size,
                              hipStream_t stream) {
    const float* x      = (const float*)d_in[0];
    const float* w_attn = (const float*)d_in[1];
    const float* w_proj = (const float*)d_in[2];
    float* out = (float*)d_out;

    unsigned short* ws  = (unsigned short*)d_ws;
    unsigned short* xb  = ws;
    unsigned short* wab = xb + (size_t)LSEQ * EMB;
    unsigned short* wpb = wab + (size_t)3 * EMB * EMB;
    unsigned short* Qb  = wpb + (size_t)EMB * EMB;
    unsigned short* Kb  = Qb + (size_t)LSEQ * EMB;
    unsigned short* Vtb = Kb + (size_t)LSEQ * EMB;
    unsigned short* Yb  = Vtb + (size_t)LSEQ * EMB;

    const int ntot = NXC + NAC + NPC;
    cvt_all<<<(ntot + 255) / 256, 256, 0, stream>>>(x, w_attn, w_proj, xb);
    gemm_qkv<<<dim3(3 * EMB / 128, LSEQ / 128), 256, 0, stream>>>(xb, wab, Qb, Kb, Vtb);
    attn_fwd<<<dim3(32, NH), 512, 0, stream>>>(Qb, Kb, Vtb, Yb);
    gemm_proj<<<dim3(EMB / 128, LSEQ / 128), 256, 0, stream>>>(Yb, wpb, out);
}

// Round 6
// 165.174 us; speedup vs baseline: 1.2255x; 1.0058x over previous
//
#include <hip/hip_runtime.h>

#define LSEQ 4096
#define EMB  1024
#define NH   16
#define HD   64

typedef __attribute__((ext_vector_type(8)))  __bf16 bf16x8;
typedef __attribute__((ext_vector_type(4)))  float f32x4;
typedef __attribute__((ext_vector_type(16))) float f32x16;
typedef __attribute__((ext_vector_type(8)))  unsigned short u16x8;
typedef __attribute__((ext_vector_type(4)))  unsigned short u16x4;
typedef __attribute__((ext_vector_type(4)))  unsigned int u32x4;

__device__ __forceinline__ unsigned short f2bf(float f) {
    union { float f; unsigned u; } v; v.f = f;
    unsigned r = v.u + 0x7fffu + ((v.u >> 16) & 1u);
    return (unsigned short)(r >> 16);
}

__device__ __forceinline__ unsigned cvt_pk_bf16(float a, float b) {
    unsigned r;
    asm("v_cvt_pk_bf16_f32 %0, %1, %2" : "=v"(r) : "v"(a), "v"(b));
    return r;
}

// exchange: x'[0:31]=x, x'[32:63]=y[l-32]; y'[0:31]=x[l+32], y'[32:63]=y
__device__ __forceinline__ void plswap(unsigned &x, unsigned &y) {
    asm volatile("v_permlane32_swap_b32 %0, %1" : "+v"(x), "+v"(y));
}

__device__ __forceinline__ f32x4 mfma16(u16x8 a, u16x8 b, f32x4 c) {
    return __builtin_amdgcn_mfma_f32_16x16x32_bf16(
        __builtin_bit_cast(bf16x8, a), __builtin_bit_cast(bf16x8, b), c, 0, 0, 0);
}

__device__ __forceinline__ f32x16 mfma32(u16x8 a, u16x8 b, f32x16 c) {
    return __builtin_amdgcn_mfma_f32_32x32x16_bf16(
        __builtin_bit_cast(bf16x8, a), __builtin_bit_cast(bf16x8, b), c, 0, 0, 0);
}

__device__ __forceinline__ void gload16(const void* g, void* l) {
    __builtin_amdgcn_global_load_lds((const __attribute__((address_space(1))) unsigned int*)g,
                                     (__attribute__((address_space(3))) unsigned int*)l,
                                     16, 0, 0);
}

// swizzled LDS read: [row][64 shorts] tile, 16B chunk c, XOR by row&7
__device__ __forceinline__ u16x8 ldsw(const char* base, int row, int c) {
    return *(const u16x8*)(base + row * 128 + ((c ^ (row & 7)) << 4));
}

// ---------------- fused fp32 -> bf16 convert ----------------
#define NXC (LSEQ * EMB / 4)
#define NAC (3 * EMB * EMB / 4)
#define NPC (EMB * EMB / 4)
__global__ __launch_bounds__(256) void cvt_all(const float* __restrict__ x,
                                               const float* __restrict__ wa,
                                               const float* __restrict__ wp,
                                               unsigned short* __restrict__ out) {
    int i = blockIdx.x * 256 + threadIdx.x;
    if (i >= NXC + NAC + NPC) return;
    const float* src;
    if (i < NXC)             src = x + (size_t)i * 4;
    else if (i < NXC + NAC)  src = wa + (size_t)(i - NXC) * 4;
    else                     src = wp + (size_t)(i - NXC - NAC) * 4;
    f32x4 v = *(const f32x4*)src;
    u16x4 o;
    o[0] = f2bf(v[0]); o[1] = f2bf(v[1]); o[2] = f2bf(v[2]); o[3] = f2bf(v[3]);
    *(u16x4*)(out + (size_t)i * 4) = o;
}

// ---------------- QKV GEMM: C[M=L,N=3E] = X[L,E] * Wattn^T, scatter epilogue ----------------
// Q pre-scaled by 0.125*log2(e): attention softmax runs in exp2 domain.
__global__ __launch_bounds__(256, 2) void gemm_qkv(const unsigned short* __restrict__ A,
                                                   const unsigned short* __restrict__ B,
                                                   unsigned short* __restrict__ Qo,
                                                   unsigned short* __restrict__ Ko,
                                                   unsigned short* __restrict__ Vto) {
    __shared__ unsigned short As[128 * 32];
    __shared__ unsigned short Bs[128 * 32];
    const int tid = threadIdx.x;
    const int lane = tid & 63;
    const int wv = tid >> 6;
    const int wm = wv >> 1, wn = wv & 1;
    const int li = lane & 15, g = lane >> 4;
    const int m0 = blockIdx.y * 128, n0 = blockIdx.x * 128;
    f32x4 acc[4][4] = {};
    for (int k0 = 0; k0 < EMB; k0 += 32) {
        #pragma unroll
        for (int c = 0; c < 2; ++c) {
            const int o = c * 4096 + tid * 16;
            const int r = o >> 6, cb = o & 63;
            gload16((const char*)A + ((size_t)(m0 + r) * EMB + k0) * 2 + cb, (char*)As + o);
            gload16((const char*)B + ((size_t)(n0 + r) * EMB + k0) * 2 + cb, (char*)Bs + o);
        }
        __syncthreads();
        u16x8 af[4], bfr[4];
        #pragma unroll
        for (int mb = 0; mb < 4; ++mb)
            af[mb] = *(const u16x8*)(As + (wm * 64 + mb * 16 + li) * 32 + g * 8);
        #pragma unroll
        for (int nb = 0; nb < 4; ++nb)
            bfr[nb] = *(const u16x8*)(Bs + (wn * 64 + nb * 16 + li) * 32 + g * 8);
        #pragma unroll
        for (int mb = 0; mb < 4; ++mb)
            #pragma unroll
            for (int nb = 0; nb < 4; ++nb)
                acc[mb][nb] = mfma16(af[mb], bfr[nb], acc[mb][nb]);
        __syncthreads();
    }
    for (int mb = 0; mb < 4; ++mb) {
        for (int nb = 0; nb < 4; ++nb) {
            for (int r = 0; r < 4; ++r) {
                const int m = m0 + wm * 64 + mb * 16 + g * 4 + r;
                const int n = n0 + wn * 64 + nb * 16 + li;
                const float v = acc[mb][nb][r];
                if (n < EMB) {
                    Qo[((size_t)(n >> 6) * LSEQ + m) * HD + (n & 63)] = f2bf(v * 0.1803368801111244f);
                } else if (n < 2 * EMB) {
                    const int c = n - EMB;
                    Ko[((size_t)(c >> 6) * LSEQ + m) * HD + (c & 63)] = f2bf(v);
                } else {
                    const int c = n - 2 * EMB;
                    Vto[((size_t)(c >> 6) * HD + (c & 63)) * LSEQ + m] = f2bf(v);
                }
            }
        }
    }
}

// ---------------- flash attention (causal), 32x32 MFMA, in-register P ----------------
// grid (32, NH), 512 thr = 8 waves: qh = w&1 (32 q rows), par = w>>1 (kv stream mod 4).
// Paired q-tiles (bx, 63-bx): 65 KV tiles per block, perfectly balanced.
// K/V staged via global_load_lds (pre-swizzled source, linear dest). No P LDS.
// LDS 64KB -> 2 blocks/CU = 16 waves/CU.
__global__ __launch_bounds__(512, 4) void attn_fwd(const unsigned short* __restrict__ Q,
                                                   const unsigned short* __restrict__ K,
                                                   const unsigned short* __restrict__ Vt,
                                                   unsigned short* __restrict__ Y) {
    __shared__ char LB[65536];   // [0,32K): K streams 0..3; [32K,64K): V streams 0..3
    const int head = blockIdx.y;
    const int tid = threadIdx.x, lane = tid & 63, w = tid >> 6;
    const int qh = w & 1, par = w >> 1;
    const int li = lane & 31, hf = lane >> 5;
    const int srow = tid >> 3, ssw = ((tid & 7) ^ (srow & 7)) * 8;   // staging row / swizzled short-col
    const unsigned short* Kh = K + (size_t)head * LSEQ * HD;
    const unsigned short* Vh = Vt + (size_t)head * HD * LSEQ;
    float* accSc = (float*)LB;             // merge overlay: 32 x 384 floats = 48KB
    float* mlSc  = (float*)(LB + 49152);   // 2 x 384 floats

    #pragma unroll 1
    for (int seg = 0; seg < 2; ++seg) {
        const int qt = seg ? (63 - (int)blockIdx.x) : (int)blockIdx.x;
        const int q0 = qt * 64;
        const int jmax = qt;
        const int R = (jmax + 4) >> 2;
        const int qrow = q0 + qh * 32 + li;
        const unsigned short* qp = Q + ((size_t)head * LSEQ + qrow) * HD + hf * 8;
        u16x8 bq[4];
        #pragma unroll
        for (int ks = 0; ks < 4; ++ks) bq[ks] = *(const u16x8*)(qp + ks * 16);
        float m_i = -1e30f, l_i = 0.f;
        f32x16 oA = {}, oB = {};   // O[q][d]: d-blocks 0 (cols 0-31) and 1 (cols 32-63)

        // stage round rnd: 4 streams, K+V, each thread 2x4 gload16
        #define STAGE(rnd)                                                              \
            _Pragma("unroll")                                                           \
            for (int i_ = 0; i_ < 4; ++i_) {                                            \
                const int j_ = (rnd) * 4 + i_;                                          \
                if (j_ <= jmax) {                                                       \
                    gload16(Kh + (size_t)(j_ * 64 + srow) * HD + ssw,                   \
                            LB + i_ * 8192 + tid * 16);                                 \
                    gload16(Vh + (size_t)srow * LSEQ + j_ * 64 + ssw,                   \
                            LB + 32768 + i_ * 8192 + tid * 16);                         \
                }                                                                       \
            }

        STAGE(0);
        __syncthreads();
        for (int rnd = 0; rnd < R; ++rnd) {
            const int j = rnd * 4 + par;
            if (j <= jmax) {
                const char* Kst = LB + par * 8192;
                const char* Vst = LB + 32768 + par * 8192;
                const int kbase = j * 64;
                // ---- QK^T swapped: S^T[kv][q], q = lane&31 ----
                f32x16 sA = {}, sB = {};
                __builtin_amdgcn_s_setprio(1);
                #pragma unroll
                for (int ks = 0; ks < 4; ++ks) {
                    const u16x8 ka0 = ldsw(Kst, li,      ks * 2 + hf);
                    const u16x8 ka1 = ldsw(Kst, 32 + li, ks * 2 + hf);
                    sA = mfma32(ka0, bq[ks], sA);
                    sB = mfma32(ka1, bq[ks], sB);
                }
                __builtin_amdgcn_s_setprio(0);
                if (j == jmax) {   // causal mask (only diagonal tile)
                    #pragma unroll
                    for (int r = 0; r < 16; ++r) {
                        const int kvl = kbase + (r & 3) + 8 * (r >> 2) + 4 * hf;
                        if (kvl > qrow)      sA[r] = -1e30f;
                        if (kvl + 32 > qrow) sB[r] = -1e30f;
                    }
                }
                // ---- softmax: in-lane (q = lane&31) + one half-swap ----
                float c0 = sA[0], c1 = sA[1], c2 = sA[2], c3 = sA[3];
                #pragma unroll
                for (int r = 4; r < 16; r += 4) {
                    c0 = fmaxf(c0, sA[r]);     c1 = fmaxf(c1, sA[r + 1]);
                    c2 = fmaxf(c2, sA[r + 2]); c3 = fmaxf(c3, sA[r + 3]);
                }
                #pragma unroll
                for (int r = 0; r < 16; r += 4) {
                    c0 = fmaxf(c0, sB[r]);     c1 = fmaxf(c1, sB[r + 1]);
                    c2 = fmaxf(c2, sB[r + 2]); c3 = fmaxf(c3, sB[r + 3]);
                }
                float mt = fmaxf(fmaxf(c0, c1), fmaxf(c2, c3));
                mt = fmaxf(mt, __shfl_xor(mt, 32));
                const bool need = !__all(mt - m_i <= 8.0f);   // T13 (exp2 domain, P<=256)
                float al = 1.0f;
                if (need) {
                    const float mn = fmaxf(m_i, mt);
                    al = exp2f(m_i - mn);
                    m_i = mn;
                }
                float s0 = 0.f, s1 = 0.f;
                unsigned uA[8], uB[8];
                #pragma unroll
                for (int wd = 0; wd < 8; ++wd) {
                    const float a0 = exp2f(sA[2 * wd] - m_i), a1 = exp2f(sA[2 * wd + 1] - m_i);
                    const float b0 = exp2f(sB[2 * wd] - m_i), b1 = exp2f(sB[2 * wd + 1] - m_i);
                    s0 += a0 + a1; s1 += b0 + b1;
                    uA[wd] = cvt_pk_bf16(a0, a1);
                    uB[wd] = cvt_pk_bf16(b0, b1);
                }
                float sum = s0 + s1;
                sum += __shfl_xor(sum, 32);
                l_i = l_i * al + sum;
                if (need) {
                    #pragma unroll
                    for (int r = 0; r < 16; ++r) {
                        const int ql = (r & 3) + 8 * (r >> 2) + 4 * hf;
                        const float af = __shfl(al, ql);
                        oA[r] *= af; oB[r] *= af;
                    }
                }
                // ---- P redistribution in-register (T12): lane<32 <-> lane>=32 ----
                plswap(uA[0], uA[2]); plswap(uA[1], uA[3]);
                plswap(uA[4], uA[6]); plswap(uA[5], uA[7]);
                plswap(uB[0], uB[2]); plswap(uB[1], uB[3]);
                plswap(uB[4], uB[6]); plswap(uB[5], uB[7]);
                const u32x4 wA0 = {uA[0], uA[1], uA[2], uA[3]};
                const u32x4 wA1 = {uA[4], uA[5], uA[6], uA[7]};
                const u32x4 wB0 = {uB[0], uB[1], uB[2], uB[3]};
                const u32x4 wB1 = {uB[4], uB[5], uB[6], uB[7]};
                const u16x8 ap0 = __builtin_bit_cast(u16x8, wA0);   // kv  0..15 slice
                const u16x8 ap1 = __builtin_bit_cast(u16x8, wA1);   // kv 16..31
                const u16x8 ap2 = __builtin_bit_cast(u16x8, wB0);   // kv 32..47
                const u16x8 ap3 = __builtin_bit_cast(u16x8, wB1);   // kv 48..63
                // ---- PV: O[q][d] += P[q][kv] * V^T[d][kv] ----
                {
                    const u16x8 bv0 = ldsw(Vst, li, 0 + hf);
                    const u16x8 bv1 = ldsw(Vst, li, 2 + hf);
                    const u16x8 bv2 = ldsw(Vst, li, 4 + hf);
                    const u16x8 bv3 = ldsw(Vst, li, 6 + hf);
                    __builtin_amdgcn_s_setprio(1);
                    oA = mfma32(ap0, bv0, oA);
                    oA = mfma32(ap1, bv1, oA);
                    oA = mfma32(ap2, bv2, oA);
                    oA = mfma32(ap3, bv3, oA);
                    __builtin_amdgcn_s_setprio(0);
                }
                {
                    const u16x8 bv0 = ldsw(Vst, 32 + li, 0 + hf);
                    const u16x8 bv1 = ldsw(Vst, 32 + li, 2 + hf);
                    const u16x8 bv2 = ldsw(Vst, 32 + li, 4 + hf);
                    const u16x8 bv3 = ldsw(Vst, 32 + li, 6 + hf);
                    __builtin_amdgcn_s_setprio(1);
                    oB = mfma32(ap0, bv0, oB);
                    oB = mfma32(ap1, bv1, oB);
                    oB = mfma32(ap2, bv2, oB);
                    oB = mfma32(ap3, bv3, oB);
                    __builtin_amdgcn_s_setprio(0);
                }
            }
            __syncthreads();                       // all waves done reading this round
            if (rnd + 1 < R) {
                STAGE(rnd + 1);
                __syncthreads();                   // staged data visible
            }
        }
        // ---- merge 4 kv streams per qh (overlay scratch on K/V buffers) ----
        if (par != 0) {
            const int widx = qh * 3 + (par - 1);
            #pragma unroll
            for (int f = 0; f < 16; ++f) {
                accSc[f * 384 + widx * 64 + lane]        = oA[f];
                accSc[(16 + f) * 384 + widx * 64 + lane] = oB[f];
            }
            mlSc[widx * 64 + lane]       = m_i;
            mlSc[384 + widx * 64 + lane] = l_i;
        }
        __syncthreads();
        if (par == 0) {
            float mk[3], lk[3];
            #pragma unroll
            for (int k = 0; k < 3; ++k) {
                mk[k] = mlSc[(qh * 3 + k) * 64 + lane];
                lk[k] = mlSc[384 + (qh * 3 + k) * 64 + lane];
            }
            const float mS = fmaxf(fmaxf(m_i, mk[0]), fmaxf(mk[1], mk[2]));
            const float f0 = exp2f(m_i - mS);
            const float f1 = exp2f(mk[0] - mS);
            const float f2 = exp2f(mk[1] - mS);
            const float f3 = exp2f(mk[2] - mS);
            const float lS = l_i * f0 + lk[0] * f1 + lk[1] * f2 + lk[2] * f3;
            #pragma unroll
            for (int r = 0; r < 16; ++r) {
                const int ql = (r & 3) + 8 * (r >> 2) + 4 * hf;
                const float g0 = __shfl(f0, ql), g1 = __shfl(f1, ql);
                const float g2 = __shfl(f2, ql), g3 = __shfl(f3, ql);
                const float gl = __shfl(lS, ql);
                float vA = oA[r] * g0, vB = oB[r] * g0;
                vA += accSc[r * 384 + (qh * 3 + 0) * 64 + lane] * g1
                    + accSc[r * 384 + (qh * 3 + 1) * 64 + lane] * g2
                    + accSc[r * 384 + (qh * 3 + 2) * 64 + lane] * g3;
                vB += accSc[(16 + r) * 384 + (qh * 3 + 0) * 64 + lane] * g1
                    + accSc[(16 + r) * 384 + (qh * 3 + 1) * 64 + lane] * g2
                    + accSc[(16 + r) * 384 + (qh * 3 + 2) * 64 + lane] * g3;
                const int row = q0 + qh * 32 + ql;
                Y[(size_t)row * EMB + head * HD + li]      = f2bf(vA / gl);
                Y[(size_t)row * EMB + head * HD + 32 + li] = f2bf(vB / gl);
            }
        }
        __syncthreads();   // scratch freed before next segment's staging
        #undef STAGE
        #define STAGE(rnd) (void)0
        #undef STAGE
        #define STAGE(rnd)                                                              \
            _Pragma("unroll")                                                           \
            for (int i_ = 0; i_ < 4; ++i_) {                                            \
                const int j_ = (rnd) * 4 + i_;                                          \
                if (j_ <= jmax) {                                                       \
                    gload16(Kh + (size_t)(j_ * 64 + srow) * HD + ssw,                   \
                            LB + i_ * 8192 + tid * 16);                                 \
                    gload16(Vh + (size_t)srow * LSEQ + j_ * 64 + ssw,                   \
                            LB + 32768 + i_ * 8192 + tid * 16);                         \
                }                                                                       \
            }
        #undef STAGE
    }
}

// ---------------- proj GEMM: out[L,E] fp32 = Y[L,E] * Wproj^T ----------------
__global__ __launch_bounds__(256, 2) void gemm_proj(const unsigned short* __restrict__ A,
                                                    const unsigned short* __restrict__ B,
                                                    float* __restrict__ C) {
    __shared__ unsigned short As[128 * 32];
    __shared__ unsigned short Bs[128 * 32];
    const int tid = threadIdx.x;
    const int lane = tid & 63;
    const int wv = tid >> 6;
    const int wm = wv >> 1, wn = wv & 1;
    const int li = lane & 15, g = lane >> 4;
    const int m0 = blockIdx.y * 128, n0 = blockIdx.x * 128;
    f32x4 acc[4][4] = {};
    for (int k0 = 0; k0 < EMB; k0 += 32) {
        #pragma unroll
        for (int c = 0; c < 2; ++c) {
            const int o = c * 4096 + tid * 16;
            const int r = o >> 6, cb = o & 63;
            gload16((const char*)A + ((size_t)(m0 + r) * EMB + k0) * 2 + cb, (char*)As + o);
            gload16((const char*)B + ((size_t)(n0 + r) * EMB + k0) * 2 + cb, (char*)Bs + o);
        }
        __syncthreads();
        u16x8 af[4], bfr[4];
        #pragma unroll
        for (int mb = 0; mb < 4; ++mb)
            af[mb] = *(const u16x8*)(As + (wm * 64 + mb * 16 + li) * 32 + g * 8);
        #pragma unroll
        for (int nb = 0; nb < 4; ++nb)
            bfr[nb] = *(const u16x8*)(Bs + (wn * 64 + nb * 16 + li) * 32 + g * 8);
        #pragma unroll
        for (int mb = 0; mb < 4; ++mb)
            #pragma unroll
            for (int nb = 0; nb < 4; ++nb)
                acc[mb][nb] = mfma16(af[mb], bfr[nb], acc[mb][nb]);
        __syncthreads();
    }
    for (int mb = 0; mb < 4; ++mb)
        for (int nb = 0; nb < 4; ++nb)
            for (int r = 0; r < 4; ++r) {
                const int m = m0 + wm * 64 + mb * 16 + g * 4 + r;
                const int n = n0 + wn * 64 + nb * 16 + li;
                C[(size_t)m * EMB + n] = acc[mb][nb][r];
            }
}

extern "C" void kernel_launch(void* const* d_in, const int* in_sizes, int n_in,
                              void* d_out, int out_size, void* d_ws, size_t ws_size,
                              hipStream_t stream) {
    const float* x      = (const float*)d_in[0];
    const float* w_attn = (const float*)d_in[1];
    const float* w_proj = (const float*)d_in[2];
    float* out = (float*)d_out;

    unsigned short* ws  = (unsigned short*)d_ws;
    unsigned short* xb  = ws;
    unsigned short* wab = xb + (size_t)LSEQ * EMB;
    unsigned short* wpb = wab + (size_t)3 * EMB * EMB;
    unsigned short* Qb  = wpb + (size_t)EMB * EMB;
    unsigned short* Kb  = Qb + (size_t)LSEQ * EMB;
    unsigned short* Vtb = Kb + (size_t)LSEQ * EMB;
    unsigned short* Yb  = Vtb + (size_t)LSEQ * EMB;

    const int ntot = NXC + NAC + NPC;
    cvt_all<<<(ntot + 255) / 256, 256, 0, stream>>>(x, w_attn, w_proj, xb);
    gemm_qkv<<<dim3(3 * EMB / 128, LSEQ / 128), 256, 0, stream>>>(xb, wab, Qb, Kb, Vtb);
    attn_fwd<<<dim3(32, NH), 512, 0, stream>>>(Qb, Kb, Vtb, Yb);
    gemm_proj<<<dim3(EMB / 128, LSEQ / 128), 256, 0, stream>>>(Yb, wpb, out);
}